// Round 1
// baseline (245.241 us; speedup 1.0000x reference)
//
#include <hip/hip_runtime.h>
#include <hip/hip_fp16.h>

#define N_NODES 50000
#define N_EDGES 800000
#define F_INN   128
#define F_HID   96
#define F_OUTT  40

typedef _Float16 half8 __attribute__((ext_vector_type(8)));
typedef float    floatx4 __attribute__((ext_vector_type(4)));

// ---------------------------------------------------------------------------
// MFMA GEMM body: T[n][96] (fp16, UNSCALED) = X[n x FI] @ W, via 16x16x32 f16.
// A = W^T tile (m=feature), B = node rows (n=node). 4 waves x 16 nodes = 64/blk.
// TIN = float (load+cvt) or __half (direct half8 load).
// ---------------------------------------------------------------------------
template <int FI, typename TIN>
__device__ __forceinline__ void mfma_gemm_body(
        const TIN* __restrict__ X, const __half* __restrict__ BTg,
        float4* __restrict__ Th4, int n, int bx) {
    __shared__ __half BTl[96 * 136];          // 26112 B
    __shared__ __half OUTl[4 * 16 * 104];     // 13312 B
    int tid = threadIdx.x;
    {   // stage BT (1632 x 16B)
        const int4* s = reinterpret_cast<const int4*>(BTg);
        int4* d = reinterpret_cast<int4*>(BTl);
        for (int i = tid; i < 96 * 136 / 8; i += 256) d[i] = s[i];
    }
    __syncthreads();

    int lane = tid & 63, w = tid >> 6;
    int lm = lane & 15, q = lane >> 4;
    int base = bx * 64 + w * 16;
    int node = base + lm;
    int nclamp = min(node, n - 1);
    const TIN* Xrow = X + (size_t)nclamp * FI;

    floatx4 cf[6];
    #pragma unroll
    for (int t = 0; t < 6; ++t) cf[t] = (floatx4){0.f, 0.f, 0.f, 0.f};

    constexpr int KS = FI / 32;
    #pragma unroll
    for (int ks = 0; ks < KS; ++ks) {
        // B-operand: lane holds k = 32*ks + q*8 .. +7 of this node's row
        half8 bv;
        if constexpr (sizeof(TIN) == 4) {
            const float4* xr = reinterpret_cast<const float4*>(Xrow + 32 * ks + q * 8);
            float4 f0 = xr[0], f1 = xr[1];
            union { half8 v; __half2 h[4]; } b;
            b.h[0] = __floats2half2_rn(f0.x, f0.y);
            b.h[1] = __floats2half2_rn(f0.z, f0.w);
            b.h[2] = __floats2half2_rn(f1.x, f1.y);
            b.h[3] = __floats2half2_rn(f1.z, f1.w);
            bv = b.v;
        } else {
            bv = *reinterpret_cast<const half8*>(Xrow + 32 * ks + q * 8);
        }
        #pragma unroll
        for (int t = 0; t < 6; ++t) {
            half8 a = *reinterpret_cast<const half8*>(
                &BTl[(t * 16 + lm) * 136 + q * 8 + 32 * ks]);
            cf[t] = __builtin_amdgcn_mfma_f32_16x16x32_f16(a, bv, cf[t], 0, 0, 0);
        }
    }

    // Epilogue: D[row=q*4+r][col=lm] = out[feature = t*16+q*4+r][node=lm].
    __half* orow = OUTl + (w * 16 + lm) * 104;
    #pragma unroll
    for (int t = 0; t < 6; ++t) {
        union { int2 i2; __half2 h[2]; } u;
        u.h[0] = __floats2half2_rn(cf[t][0], cf[t][1]);
        u.h[1] = __floats2half2_rn(cf[t][2], cf[t][3]);
        *reinterpret_cast<int2*>(&orow[t * 16 + q * 4]) = u.i2;
    }
    // Same-wave LDS round-trip: coalesced fp16 row store (12 x float4 per node).
    #pragma unroll
    for (int R = 0; R < 3; ++R) {
        int nl = lane >> 2, c = (lane & 3) + 4 * R;
        float4 v = *reinterpret_cast<const float4*>(&OUTl[(w * 16 + nl) * 104 + c * 8]);
        int gn = base + nl;
        if (gn < n) Th4[(size_t)gn * 12 + c] = v;
    }
}

// ---------------------------------------------------------------------------
// Fused: count (blocks [0,nCB)) + gemm L1 (blocks [nCB, nCB+GB)) — independent.
// ---------------------------------------------------------------------------
__global__ __launch_bounds__(256) void count_gemm1_kernel(
        const int* __restrict__ dst, int* __restrict__ counts4, int* __restrict__ rank,
        int e, const float* __restrict__ X, const __half* __restrict__ BT1,
        float4* __restrict__ Th4, int n, int nCB) {
    if ((int)blockIdx.x < nCB) {
        int i = blockIdx.x * 256 + threadIdx.x;
        if (i < e) rank[i] = atomicAdd(&counts4[dst[i] * 4 + (i & 3)], 1);
    } else {
        mfma_gemm_body<F_INN, float>(X, BT1, Th4, n, blockIdx.x - nCB);
    }
}

template <int FI, typename TIN>
__global__ __launch_bounds__(256) void mfma_gemm_kernel(
        const TIN* __restrict__ X, const __half* __restrict__ BTg,
        float4* __restrict__ Th4, int n) {
    mfma_gemm_body<FI, TIN>(X, BTg, Th4, n, blockIdx.x);
}

// ---------------------------------------------------------------------------
// Weight transpose + fp16: W[K x 96] -> BT[96][136] (pad 8). W1 & W2 together.
// ---------------------------------------------------------------------------
__global__ void wt_kernel(const float* __restrict__ W1, const float* __restrict__ W2,
                          __half* __restrict__ BT1, __half* __restrict__ BT2) {
    int i = blockIdx.x * 256 + threadIdx.x;
    if (i < 96 * 128) {
        int j = i / 128, k = i - j * 128;
        BT1[j * 136 + k] = __float2half(W1[k * 96 + j]);
    } else if (i < 96 * 128 + 96 * 96) {
        int t = i - 96 * 128;
        int j = t / 96, k = t - j * 96;
        BT2[j * 136 + k] = __float2half(W2[k * 96 + j]);
    }
}

// ---------------------------------------------------------------------------
// Scan phase 1: per-block exclusive scan of node degrees; dinv; block sums.
// ---------------------------------------------------------------------------
__global__ __launch_bounds__(1024) void scan_local_kernel(
        const int4* __restrict__ counts4, int* __restrict__ row_start,
        float* __restrict__ dinv, int* __restrict__ blk_sums, int n) {
    __shared__ int wave_sums[16];
    int tid = threadIdx.x, lane = tid & 63, wid = tid >> 6;
    int i = blockIdx.x * 1024 + tid;
    int v = 0;
    if (i < n) {
        int4 c = counts4[i];
        v = c.x + c.y + c.z + c.w;
    }
    int val = v;
    #pragma unroll
    for (int off = 1; off < 64; off <<= 1) {
        int u = __shfl_up(val, off, 64);
        if (lane >= off) val += u;
    }
    if (lane == 63) wave_sums[wid] = val;
    __syncthreads();
    if (wid == 0) {
        int w = (lane < 16) ? wave_sums[lane] : 0;
        #pragma unroll
        for (int off = 1; off < 16; off <<= 1) {
            int u = __shfl_up(w, off, 64);
            if (lane >= off) w += u;
        }
        if (lane < 16) wave_sums[lane] = w;
    }
    __syncthreads();
    int excl = ((wid == 0) ? 0 : wave_sums[wid - 1]) + (val - v);
    if (i < n) {
        row_start[i] = excl;                  // local; global offset in phase 2
        dinv[i] = rsqrtf((float)(v + 1));     // +1 self loop
    }
    if (tid == 0) blk_sums[blockIdx.x] = wave_sums[15];
}

// ---------------------------------------------------------------------------
// Scan phase 2+3 fused: every block redundantly scans the <=64 block sums,
// applies its own offset, emits per-shard bases base4. Block 0 writes total.
// ---------------------------------------------------------------------------
__global__ __launch_bounds__(1024) void scan_apply_kernel(
        int* __restrict__ row_start, const int* __restrict__ blk_sums,
        const int4* __restrict__ counts4, int4* __restrict__ base4, int n, int nblk) {
    __shared__ int s_my, s_tot;
    int tid = threadIdx.x;
    if (tid < 64) {
        int v = (tid < nblk) ? blk_sums[tid] : 0;
        int val = v;
        #pragma unroll
        for (int off = 1; off < 64; off <<= 1) {
            int u = __shfl_up(val, off, 64);
            if (tid >= off) val += u;
        }
        if (tid == (int)blockIdx.x) s_my = val - v;   // exclusive prefix
        if (tid == 63) s_tot = val;                   // grand total == E
    }
    __syncthreads();
    int i = blockIdx.x * 1024 + tid;
    if (i < n) {
        int4 c = counts4[i];
        int b = row_start[i] + s_my;
        row_start[i] = b;
        base4[i] = make_int4(b, b + c.x, b + c.x + c.y, b + c.x + c.y + c.z);
    }
    if (blockIdx.x == 0 && tid == 0) row_start[n] = s_tot;
}

// Atomic-free fill: pos = base4[dst].shard + rank.  One scattered 4B store.
__global__ void fill_csr_kernel(const int* __restrict__ src, const int* __restrict__ dst,
                                const int* __restrict__ rank, const int* __restrict__ base4,
                                int* __restrict__ csr_src, int e) {
    int i = blockIdx.x * blockDim.x + threadIdx.x;
    if (i >= e) return;
    csr_src[base4[dst[i] * 4 + (i & 3)] + rank[i]] = src[i];
}

// ---------------------------------------------------------------------------
// Aggregation: one wave per node.  Wide-gather layout: a T row is 96 fp16 =
// 192 B = 12 x 16 B, so 12 lanes x half8 cover one edge and the wave covers
// FIVE edges per iteration (lanes 60..63 idle, 6% waste vs 25% before).
// Self-loop is a virtual edge at position idx-1 with weight dinv[node].
// Two ITERs per round keep 10 gathers in flight.
// Epilogue: cross-lane reduce over the 5 edge slots; lanes 0..11 hold the
// full 96-feature row.  H[d] = relu(dinv[d]*acc + b), fp16 out — or, when
// FUSE_OUT, the output GEMM (H @ Wout + bout) runs in-block from LDS.
// ---------------------------------------------------------------------------
template <bool FUSE_OUT>
__global__ __launch_bounds__(256) void agg_kernel(
        const __half2* __restrict__ T, const int* __restrict__ row_start,
        const int* __restrict__ csr_src, const float* __restrict__ dinv,
        const float* __restrict__ bias, __half2* __restrict__ H,
        const float* __restrict__ Wout, const float* __restrict__ bout,
        float* __restrict__ out, int n) {
    __shared__ float Wl[96 * 40];      // 15360 B (used only when FUSE_OUT)
    __shared__ float Hs[4][96];        //  1536 B (used only when FUSE_OUT)
    int tid = threadIdx.x;
    if (FUSE_OUT) {                    // stage Wout once per block (no sync needed yet)
        const float4* ws = reinterpret_cast<const float4*>(Wout);
        float4* wd = reinterpret_cast<float4*>(Wl);
        for (int i = tid; i < 960; i += 256) wd[i] = ws[i];
    }

    int lane = tid & 63, wid = tid >> 6;
    int node = __builtin_amdgcn_readfirstlane(blockIdx.x * 4 + wid);
    int nodec = min(node, n - 1);
    int e = lane / 12;                 // edge slot 0..4; lanes 60..63 -> e=5 (idle)
    int g = lane - e * 12;             // 16B chunk within the 192B row

    float dn = dinv[nodec];
    int idx = row_start[nodec], end = row_start[nodec + 1];
    const __half* Tb = reinterpret_cast<const __half*>(T);

    float acc[8];
    #pragma unroll
    for (int j = 0; j < 8; ++j) acc[j] = 0.f;

    auto ITER = [&](int base) {
        int p = base + e;
        int s = nodec; float w = 0.f;
        if (e < 5) {
            if (p >= idx && p < end) { s = csr_src[p]; w = dinv[s]; }
            else if (p == idx - 1)   { w = dn; }     // self-loop (base==idx-1, e==0)
        }
        union { half8 v; __half2 h[4]; } u;
        u.v = *reinterpret_cast<const half8*>(Tb + (size_t)s * 96 + g * 8);
        #pragma unroll
        for (int q = 0; q < 4; ++q) {
            float2 f = __half22float2(u.h[q]);
            acc[2 * q]     = fmaf(w, f.x, acc[2 * q]);
            acc[2 * q + 1] = fmaf(w, f.y, acc[2 * q + 1]);
        }
    };
    for (int base = idx - 1; base < end; base += 10) { ITER(base); ITER(base + 5); }

    // Reduce the 5 edge slots: lanes {g, g+12, g+24, g+36, g+48} hold slot sums.
    float red[8];
    #pragma unroll
    for (int j = 0; j < 8; ++j) {
        float t = acc[j];
        t += __shfl(acc[j], lane + 12);
        t += __shfl(acc[j], lane + 24);
        t += __shfl(acc[j], lane + 36);
        t += __shfl(acc[j], lane + 48);
        red[j] = t;
    }

    if (lane < 12 && node < n) {
        const float4* bp = reinterpret_cast<const float4*>(bias);
        float4 b0 = bp[2 * lane], b1 = bp[2 * lane + 1];
        float r[8];
        r[0] = fmaxf(fmaf(dn, red[0], b0.x), 0.f);
        r[1] = fmaxf(fmaf(dn, red[1], b0.y), 0.f);
        r[2] = fmaxf(fmaf(dn, red[2], b0.z), 0.f);
        r[3] = fmaxf(fmaf(dn, red[3], b0.w), 0.f);
        r[4] = fmaxf(fmaf(dn, red[4], b1.x), 0.f);
        r[5] = fmaxf(fmaf(dn, red[5], b1.y), 0.f);
        r[6] = fmaxf(fmaf(dn, red[6], b1.z), 0.f);
        r[7] = fmaxf(fmaf(dn, red[7], b1.w), 0.f);
        if (!FUSE_OUT) {
            union { int4 i4; __half2 h[4]; } o;
            o.h[0] = __floats2half2_rn(r[0], r[1]);
            o.h[1] = __floats2half2_rn(r[2], r[3]);
            o.h[2] = __floats2half2_rn(r[4], r[5]);
            o.h[3] = __floats2half2_rn(r[6], r[7]);
            *reinterpret_cast<int4*>(H + (size_t)node * 48 + lane * 4) = o.i4;
        } else {
            #pragma unroll
            for (int j = 0; j < 8; ++j) Hs[wid][lane * 8 + j] = r[j];
        }
    }

    if (FUSE_OUT) {
        __syncthreads();               // all 256 threads reach (no early returns)
        if (tid < 160) {               // 4 nodes x 40 outputs
            int nn = tid / 40, j = tid - nn * 40;
            int gn = blockIdx.x * 4 + nn;
            if (gn < n) {
                float a = bout[j];
                const float* hrow = Hs[nn];
                #pragma unroll 8
                for (int k = 0; k < 96; ++k) a = fmaf(hrow[k], Wl[k * 40 + j], a);
                out[(size_t)gn * 40 + j] = a;
            }
        }
    }
}

// ---------------------------------------------------------------------------

extern "C" void kernel_launch(void* const* d_in, const int* in_sizes, int n_in,
                              void* d_out, int out_size, void* d_ws, size_t ws_size,
                              hipStream_t stream) {
    const float* x    = (const float*)d_in[0];
    const int*   ei   = (const int*)d_in[1];
    const float* W1   = (const float*)d_in[2];
    const float* b1   = (const float*)d_in[3];
    const float* W2   = (const float*)d_in[4];
    const float* b2   = (const float*)d_in[5];
    const float* Wout = (const float*)d_in[6];
    const float* bout = (const float*)d_in[7];
    float*       out  = (float*)d_out;

    const int* src = ei;            // edge_index[0]
    const int* dst = ei + N_EDGES;  // edge_index[1]

    char* ws = (char*)d_ws;
    size_t off = 0;
    auto alloc = [&](size_t bytes) {
        size_t o = off;
        off = (off + bytes + 511) & ~(size_t)511;
        return (void*)(ws + o);
    };
    int*     counts4   = (int*)    alloc((size_t)N_NODES * 4 * sizeof(int));
    int4*    base4     = (int4*)   alloc((size_t)N_NODES * sizeof(int4));
    int*     row_start = (int*)    alloc((N_NODES + 1) * sizeof(int));
    float*   dinv      = (float*)  alloc(N_NODES * sizeof(float));
    int*     blk_sums  = (int*)    alloc(64 * sizeof(int));
    int*     rank      = (int*)    alloc((size_t)N_EDGES * sizeof(int));
    int*     csr_src   = (int*)    alloc((size_t)N_EDGES * sizeof(int));
    __half*  BT1       = (__half*) alloc((size_t)96 * 136 * sizeof(__half));
    __half*  BT2       = (__half*) alloc((size_t)96 * 136 * sizeof(__half));
    __half2* Th        = (__half2*)alloc((size_t)N_NODES * 48 * sizeof(__half2));
    __half2* Hh        = (__half2*)alloc((size_t)N_NODES * 48 * sizeof(__half2));

    const int NSCAN = (N_NODES + 1023) / 1024;   // 49
    const int CB    = (N_EDGES + 255) / 256;     // 3125 count blocks
    const int GB    = (N_NODES + 63) / 64;       // 782 gemm blocks
    const int AB    = (N_NODES + 3) / 4;         // 12500 agg blocks

    // --- prep ---
    hipMemsetAsync(counts4, 0, (size_t)N_NODES * 4 * sizeof(int), stream);
    wt_kernel<<<(96 * 128 + 96 * 96 + 255) / 256, 256, 0, stream>>>(W1, W2, BT1, BT2);

    // --- fused: edge counting + layer-1 GEMM (independent) ---
    count_gemm1_kernel<<<CB + GB, 256, 0, stream>>>(
        dst, counts4, rank, N_EDGES, x, BT1, (float4*)Th, N_NODES, CB);

    // --- scan (2 launches) + fill ---
    scan_local_kernel<<<NSCAN, 1024, 0, stream>>>(
        (const int4*)counts4, row_start, dinv, blk_sums, N_NODES);
    scan_apply_kernel<<<NSCAN, 1024, 0, stream>>>(
        row_start, blk_sums, (const int4*)counts4, base4, N_NODES, NSCAN);
    fill_csr_kernel<<<CB, 256, 0, stream>>>(
        src, dst, rank, (const int*)base4, csr_src, N_EDGES);

    // --- layer 1 aggregation -> H (fp16) ---
    agg_kernel<false><<<AB, 256, 0, stream>>>(
        Th, row_start, csr_src, dinv, b1, Hh, Wout, bout, out, N_NODES);

    // --- layer 2: GEMM (fp16 in) + aggregation fused with output GEMM ---
    mfma_gemm_kernel<F_HID, __half><<<GB, 256, 0, stream>>>(
        (const __half*)Hh, BT2, (float4*)Th, N_NODES);
    agg_kernel<true><<<AB, 256, 0, stream>>>(
        Th, row_start, csr_src, dinv, b2, Hh, Wout, bout, out, N_NODES);
}